// Round 6
// baseline (163.224 us; speedup 1.0000x reference)
//
#include <hip/hip_runtime.h>
#include <math.h>

#define N_NODES 100000
#define E_EDGES 800000
#define NT 16                 // nodes per tile (one wave per tile)
#define NTILES (N_NODES / NT) // 6250
#define OFF_MU 6400000L
#define OFF_LV 8000000L

typedef __attribute__((ext_vector_type(8))) short short8;
typedef __attribute__((ext_vector_type(4))) float f32x4;
typedef __attribute__((ext_vector_type(4))) float float4v;

// weight fragment regions (in halves; each frag = 64 lanes * 8 halves = 512)
#define SW_AGG 0
#define SW_FUS 8192
#define SW_W1  24576
#define SW_W2  32768
#define SW_W3  36864
#define SW_W4  40960
#define SW_TOT 49152

__global__ void build_row_start(const int* __restrict__ edge_dst,
                                int* __restrict__ row_start) {
    int e = blockIdx.x * blockDim.x + threadIdx.x;
    if (e >= E_EDGES) return;
    int d = edge_dst[e];
    int dprev = (e == 0) ? -1 : edge_dst[e - 1];
    for (int n = dprev + 1; n <= d; ++n) row_start[n] = e;
    if (e == E_EDGES - 1) {
        for (int n = d + 1; n <= N_NODES; ++n) row_start[n] = E_EDGES;
    }
}

// ---- gather kernel: one wave per node, no LDS, high occupancy ----
__global__ __launch_bounds__(256, 8) void gather_mean(
    const float* __restrict__ x,
    const int* __restrict__ edge_src,
    const int* __restrict__ row_start,
    float* __restrict__ avg_out)
{
    const int wv   = (int)((blockIdx.x * blockDim.x + threadIdx.x) >> 6);
    const int lane = (int)(threadIdx.x & 63);
    if (wv >= N_NODES) return;

    const int e0 = row_start[wv];
    const int e1 = row_start[wv + 1];

    // lane-parallel preload of up to 64 edge indices
    int p = e0 + lane;
    p = p < E_EDGES ? p : E_EDGES - 1;
    const int iv = edge_src[p];

    float s0=0.f,s1=0.f,s2=0.f,s3=0.f,s4=0.f,s5=0.f,s6=0.f,s7=0.f;
    for (int e = e0; e < e1; e += 8) {
        float v[8];
        #pragma unroll
        for (int i = 0; i < 8; ++i) {
            const int ee = e + i;
            const bool live = ee < e1;
            const int te = ee - e0;
            int ix;
            if (te < 64) ix = __builtin_amdgcn_readlane(iv, te);   // te wave-uniform
            else {
                int ec = ee < E_EDGES - 1 ? ee : E_EDGES - 1;
                ix = edge_src[ec];
            }
            ix = live ? ix : 0;
            float t = x[(long)ix * 64 + lane];
            v[i] = live ? t : 0.0f;
        }
        s0 += v[0]; s1 += v[1]; s2 += v[2]; s3 += v[3];
        s4 += v[4]; s5 += v[5]; s6 += v[6]; s7 += v[7];
    }
    const float sum = ((s0 + s1) + (s2 + s3)) + ((s4 + s5) + (s6 + s7));
    avg_out[(long)wv * 64 + lane] = sum / fmaxf((float)(e1 - e0), 1.0f);
}

__device__ __forceinline__ unsigned short f2bf(float f) {
    unsigned u = __float_as_uint(f);
    unsigned r = u + 0x7FFFu + ((u >> 16) & 1u);
    return (unsigned short)(r >> 16);
}
__device__ __forceinline__ float bf2f(unsigned short h) {
    return __uint_as_float(((unsigned)h) << 16);
}
__device__ __forceinline__ void split8(const float* v, short8& hi, short8& lo) {
    #pragma unroll
    for (int i = 0; i < 8; ++i) {
        unsigned short h = f2bf(v[i]);
        hi[i] = (short)h;
        lo[i] = (short)f2bf(v[i] - bf2f(h));
    }
}

// XOR-swizzled activation tile address (16 rows x 64 f32 per wave)
__device__ __forceinline__ int actaddr(int row, int col) {
    return row * 64 + ((((col >> 2)) ^ (row & 15)) << 2) + (col & 3);
}

// stage one weight matrix into LDS as bf16 hi/lo B-fragments
__device__ void stage_w(const float* __restrict__ W, int Ksrc, int NC,
                        int NKT, int NJT_local, int jt_off, int NF_tot,
                        int rb, short* sw, int tid) {
    const int tot = NJT_local * NKT * 64;
    for (int s = tid; s < tot; s += 512) {
        int f = s >> 6, l = s & 63;
        int jtl = f / NKT, kt = f - jtl * NKT;
        int col = jtl * 16 + (l & 15);
        int k0 = kt * 32 + ((l >> 4) << 3);
        float v[8];
        #pragma unroll
        for (int i = 0; i < 8; ++i)
            v[i] = (k0 + i < Ksrc) ? W[(k0 + i) * NC + col] : 0.0f;
        short8 hi, lo; split8(v, hi, lo);
        int fg = (jt_off + jtl) * NKT + kt;
        *(short8*)&sw[rb + fg * 512 + l * 8] = hi;
        *(short8*)&sw[rb + (NF_tot + fg) * 512 + l * 8] = lo;
    }
}

// build A-frags (kt=0,1) for rows base..base+15 of a row-major [*,64] matrix
__device__ __forceinline__ void frags_from_global(const float* __restrict__ rowmat,
                                                  long base, int lane,
                                                  short8* hi, short8* lo) {
    const int row = lane & 15, ko = (lane >> 4) * 8;
    const float* r = rowmat + (base + row) * 64;
    float v[8];
    *(float4v*)&v[0] = *(const float4v*)&r[ko];
    *(float4v*)&v[4] = *(const float4v*)&r[ko + 4];
    split8(v, hi[0], lo[0]);
    *(float4v*)&v[0] = *(const float4v*)&r[32 + ko];
    *(float4v*)&v[4] = *(const float4v*)&r[32 + ko + 4];
    split8(v, hi[1], lo[1]);
}

template<int NKT>
__device__ __forceinline__ void frags_from_act(const float* actw, int lane,
                                               short8* hi, short8* lo) {
    const int row = lane & 15, ko = (lane >> 4) * 8;
    #pragma unroll
    for (int kt = 0; kt < NKT; ++kt) {
        float v[8];
        *(float4v*)&v[0] = *(const float4v*)&actw[actaddr(row, kt * 32 + ko)];
        *(float4v*)&v[4] = *(const float4v*)&actw[actaddr(row, kt * 32 + ko + 4)];
        split8(v, hi[kt], lo[kt]);
    }
}

template<int NJT, int NKT>
__device__ __forceinline__ void gemm_frag(const short8* ahi, const short8* alo,
                                          const short* sw, int rb,
                                          const float* bj, f32x4* c, int lane) {
    #pragma unroll
    for (int jt = 0; jt < NJT; ++jt) {
        f32x4 acc = { bj[jt], bj[jt], bj[jt], bj[jt] };
        #pragma unroll
        for (int kt = 0; kt < NKT; ++kt) {
            const short8 bhi = *(const short8*)&sw[rb + (jt * NKT + kt) * 512 + lane * 8];
            const short8 blo = *(const short8*)&sw[rb + (NJT * NKT + jt * NKT + kt) * 512 + lane * 8];
            acc = __builtin_amdgcn_mfma_f32_16x16x32_bf16(ahi[kt], bhi, acc, 0, 0, 0);
            acc = __builtin_amdgcn_mfma_f32_16x16x32_bf16(alo[kt], bhi, acc, 0, 0, 0);
            acc = __builtin_amdgcn_mfma_f32_16x16x32_bf16(ahi[kt], blo, acc, 0, 0, 0);
        }
        c[jt] = acc;
    }
}

__device__ __forceinline__ void write_act(float* actw, const f32x4* c, int lane) {
    const int g = lane >> 4, col0 = lane & 15;
    #pragma unroll
    for (int jt = 0; jt < 4; ++jt)
        #pragma unroll
        for (int r = 0; r < 4; ++r)
            actw[actaddr(g * 4 + r, jt * 16 + col0)] = fmaxf(c[jt][r], 0.0f);
}

// edge index helper for fused fallback path
__device__ __forceinline__ int get_idx(int te, int iv0, int iv1, int iv2,
                                       const int* __restrict__ edge_src, int E0) {
    if (te < 192) {
        const int w = te >> 6, l = te & 63;
        const int v = (w == 0) ? iv0 : ((w == 1) ? iv1 : iv2);
        return __builtin_amdgcn_readlane(v, l);
    }
    return edge_src[E0 + te];
}

// SPLIT=true: neighbor averages precomputed in avgp (gather_mean kernel).
// SPLIT=false: fused gather fallback (r5 path) when ws is too small.
template<bool SPLIT>
__global__ __launch_bounds__(512) void vae_mfma(
    const float* __restrict__ x,
    const int* __restrict__ edge_src,
    const float* __restrict__ avgp,
    const float* __restrict__ eps,
    const float* __restrict__ W_agg, const float* __restrict__ b_agg,
    const float* __restrict__ W_fus, const float* __restrict__ b_fus,
    const float* __restrict__ W1,  const float* __restrict__ b1,
    const float* __restrict__ W21, const float* __restrict__ b21,
    const float* __restrict__ W22, const float* __restrict__ b22,
    const float* __restrict__ W3,  const float* __restrict__ b3,
    const float* __restrict__ W4,  const float* __restrict__ b4,
    const int* __restrict__ row_start,
    float* __restrict__ out)
{
    __shared__ __align__(16) short s_w[SW_TOT];     // 96 KB
    __shared__ __align__(16) float s_act[8 * 1024]; // 32 KB

    const int tid = threadIdx.x;

    // ---- stage all weights as bf16 hi/lo fragments ----
    stage_w(W_agg, 64, 64, 2, 4, 0,  8, SW_AGG, s_w, tid);
    stage_w(W_fus, 128, 64, 4, 4, 0, 16, SW_FUS, s_w, tid);
    stage_w(W1,   64, 64, 2, 4, 0,  8, SW_W1,  s_w, tid);
    stage_w(W21,  64, 16, 2, 1, 0,  4, SW_W2,  s_w, tid);
    stage_w(W22,  64, 16, 2, 1, 1,  4, SW_W2,  s_w, tid);
    stage_w(W3,   16, 64, 1, 4, 0,  4, SW_W3,  s_w, tid);
    stage_w(W4,   64, 64, 2, 4, 0,  8, SW_W4,  s_w, tid);
    __syncthreads();

    const int lane = tid & 63;
    const int wid  = tid >> 6;
    float* actw = s_act + wid * 1024;
    const int gw = blockIdx.x * 8 + wid;
    const int nwaves = gridDim.x * 8;
    const int cj = lane & 15, g = lane >> 4;

    // ---- per-lane bias registers ----
    float bja[4], bjf[4], bj1[4], bj2[2], bj3[4], bj4[4];
    #pragma unroll
    for (int jt = 0; jt < 4; ++jt) {
        bja[jt] = b_agg[jt * 16 + cj];
        bjf[jt] = b_fus[jt * 16 + cj];
        bj1[jt] = b1[jt * 16 + cj];
        bj3[jt] = b3[jt * 16 + cj];
        bj4[jt] = b4[jt * 16 + cj];
    }
    bj2[0] = b21[cj];
    bj2[1] = b22[cj];

    for (int t = gw; t < NTILES; t += nwaves) {
        const int base = t * NT;

        short8 ahi[4], alo[4];
        f32x4 c4[4];

        if (SPLIT) {
            // ---- agg A-frags directly from precomputed avg ----
            frags_from_global(avgp, base, lane, ahi, alo);
        } else {
            // ---- fused gather: segment mean into act tile (8-deep MLP) ----
            int idx17 = base + (lane < 17 ? lane : 16);
            int rsv = row_start[idx17];
            const int E0 = __builtin_amdgcn_readlane(rsv, 0);

            int p0 = E0 + lane;       p0 = p0 < E_EDGES - 1 ? p0 : E_EDGES - 1;
            int p1 = E0 + 64 + lane;  p1 = p1 < E_EDGES - 1 ? p1 : E_EDGES - 1;
            int p2 = E0 + 128 + lane; p2 = p2 < E_EDGES - 1 ? p2 : E_EDGES - 1;
            const int iv0 = edge_src[p0];
            const int iv1 = edge_src[p1];
            const int iv2 = edge_src[p2];

            for (int n = 0; n < NT; ++n) {
                const int e0 = __builtin_amdgcn_readlane(rsv, n);
                const int e1 = __builtin_amdgcn_readlane(rsv, n + 1);
                float s0=0.f,s1=0.f,s2=0.f,s3=0.f,s4=0.f,s5=0.f,s6=0.f,s7=0.f;
                if (e1 > e0) {
                    int e = e0;
                    for (; e + 8 <= e1; e += 8) {
                        const int te = e - E0;
                        const int i0 = get_idx(te + 0, iv0, iv1, iv2, edge_src, E0);
                        const int i1 = get_idx(te + 1, iv0, iv1, iv2, edge_src, E0);
                        const int i2 = get_idx(te + 2, iv0, iv1, iv2, edge_src, E0);
                        const int i3 = get_idx(te + 3, iv0, iv1, iv2, edge_src, E0);
                        const int i4 = get_idx(te + 4, iv0, iv1, iv2, edge_src, E0);
                        const int i5 = get_idx(te + 5, iv0, iv1, iv2, edge_src, E0);
                        const int i6 = get_idx(te + 6, iv0, iv1, iv2, edge_src, E0);
                        const int i7 = get_idx(te + 7, iv0, iv1, iv2, edge_src, E0);
                        s0 += x[(long)i0 * 64 + lane];
                        s1 += x[(long)i1 * 64 + lane];
                        s2 += x[(long)i2 * 64 + lane];
                        s3 += x[(long)i3 * 64 + lane];
                        s4 += x[(long)i4 * 64 + lane];
                        s5 += x[(long)i5 * 64 + lane];
                        s6 += x[(long)i6 * 64 + lane];
                        s7 += x[(long)i7 * 64 + lane];
                    }
                    if (e < e1) {
                        #pragma unroll
                        for (int i = 0; i < 7; ++i) {
                            int ec = e + i;
                            const bool live = ec < e1;
                            ec = live ? ec : e0;
                            const int ix = get_idx(ec - E0, iv0, iv1, iv2, edge_src, E0);
                            float v = x[(long)ix * 64 + lane];
                            v = live ? v : 0.0f;
                            switch (i & 7) {
                                case 0: s0 += v; break; case 1: s1 += v; break;
                                case 2: s2 += v; break; case 3: s3 += v; break;
                                case 4: s4 += v; break; case 5: s5 += v; break;
                                case 6: s6 += v; break;
                            }
                        }
                    }
                }
                const float sum = ((s0 + s1) + (s2 + s3)) + ((s4 + s5) + (s6 + s7));
                actw[actaddr(n, lane)] = sum / fmaxf((float)(e1 - e0), 1.0f);
            }
            frags_from_act<2>(actw, lane, ahi, alo);
        }

        // ---- ne = relu(avg @ W_agg + b_agg) ----
        gemm_frag<4, 2>(ahi, alo, s_w, SW_AGG, bja, c4, lane);
        write_act(actw, c4, lane);                 // ne

        // ---- xf = relu([x, ne] @ W_fus + b_fus) ----
        frags_from_global(x, base, lane, ahi, alo);        // x part (kt 0,1)
        frags_from_act<2>(actw, lane, ahi + 2, alo + 2);   // ne part (kt 2,3)
        gemm_frag<4, 4>(ahi, alo, s_w, SW_FUS, bjf, c4, lane);
        write_act(actw, c4, lane);                 // xf

        // ---- h1 = relu(xf @ W1 + b1) ----
        frags_from_act<2>(actw, lane, ahi, alo);
        gemm_frag<4, 2>(ahi, alo, s_w, SW_W1, bj1, c4, lane);
        write_act(actw, c4, lane);                 // h1

        // ---- mu / logvar (combined 64x32 GEMM: jt0=mu, jt1=lv) ----
        frags_from_act<2>(actw, lane, ahi, alo);
        f32x4 c2[2];
        gemm_frag<2, 2>(ahi, alo, s_w, SW_W2, bj2, c2, lane);

        // ---- store mu/lv; z = mu + eps*exp(0.5*lv) ----
        float z4[4];
        #pragma unroll
        for (int r = 0; r < 4; ++r) {
            const long node = base + g * 4 + r;
            out[OFF_MU + node * 16 + cj] = c2[0][r];
            out[OFF_LV + node * 16 + cj] = c2[1][r];
            z4[r] = c2[0][r] + eps[node * 16 + cj] * __expf(0.5f * c2[1][r]);
        }

        // ---- h3 = relu(z @ W3 + b3), K padded to 32 ----
        #pragma unroll
        for (int r = 0; r < 4; ++r)
            actw[actaddr(g * 4 + r, cj)] = z4[r];
        {
            short8 zh = {0,0,0,0,0,0,0,0}, zl = {0,0,0,0,0,0,0,0};
            if (lane < 32) {
                float v[8];
                const int row = lane & 15, ko = (lane >> 4) * 8;  // 0 or 8
                *(float4v*)&v[0] = *(const float4v*)&actw[actaddr(row, ko)];
                *(float4v*)&v[4] = *(const float4v*)&actw[actaddr(row, ko + 4)];
                split8(v, zh, zl);
            }
            gemm_frag<4, 1>(&zh, &zl, s_w, SW_W3, bj3, c4, lane);
        }
        write_act(actw, c4, lane);                 // h3

        // ---- recon = sigmoid(h3 @ W4 + b4) ----
        frags_from_act<2>(actw, lane, ahi, alo);
        gemm_frag<4, 2>(ahi, alo, s_w, SW_W4, bj4, c4, lane);
        #pragma unroll
        for (int jt = 0; jt < 4; ++jt)
            #pragma unroll
            for (int r = 0; r < 4; ++r) {
                const float s = 1.0f / (1.0f + __expf(-c4[jt][r]));
                out[(long)(base + g * 4 + r) * 64 + jt * 16 + cj] = s;
            }
    }
}

extern "C" void kernel_launch(void* const* d_in, const int* in_sizes, int n_in,
                              void* d_out, int out_size, void* d_ws, size_t ws_size,
                              hipStream_t stream) {
    const float* x        = (const float*)d_in[0];
    const int*   edge_src = (const int*)  d_in[1];
    const int*   edge_dst = (const int*)  d_in[2];
    const float* eps      = (const float*)d_in[3];
    const float* W_agg    = (const float*)d_in[4];
    const float* b_agg    = (const float*)d_in[5];
    const float* W_fus    = (const float*)d_in[6];
    const float* b_fus    = (const float*)d_in[7];
    const float* W1       = (const float*)d_in[8];
    const float* b1       = (const float*)d_in[9];
    const float* W21      = (const float*)d_in[10];
    const float* b21      = (const float*)d_in[11];
    const float* W22      = (const float*)d_in[12];
    const float* b22      = (const float*)d_in[13];
    const float* W3       = (const float*)d_in[14];
    const float* b3       = (const float*)d_in[15];
    const float* W4       = (const float*)d_in[16];
    const float* b4       = (const float*)d_in[17];
    float* out = (float*)d_out;

    int* row_start = (int*)d_ws;
    build_row_start<<<(E_EDGES + 255) / 256, 256, 0, stream>>>(edge_dst, row_start);

    const size_t avg_off = 1 << 20;   // row_start uses 400004 B
    const size_t need = avg_off + (size_t)N_NODES * 64 * sizeof(float);

    if (ws_size >= need) {
        float* avg = (float*)((char*)d_ws + avg_off);
        gather_mean<<<(N_NODES * 64 + 255) / 256, 256, 0, stream>>>(x, edge_src, row_start, avg);
        vae_mfma<true><<<256, 512, 0, stream>>>(x, edge_src, avg, eps,
                                                W_agg, b_agg, W_fus, b_fus,
                                                W1, b1, W21, b21, W22, b22,
                                                W3, b3, W4, b4, row_start, out);
    } else {
        vae_mfma<false><<<256, 512, 0, stream>>>(x, edge_src, (const float*)nullptr, eps,
                                                 W_agg, b_agg, W_fus, b_fus,
                                                 W1, b1, W21, b21, W22, b22,
                                                 W3, b3, W4, b4, row_start, out);
    }
}

// Round 7
// 91.604 us; speedup vs baseline: 1.7818x; 1.7818x over previous
//
#include <hip/hip_runtime.h>
#include <math.h>

#define N_NODES 100000
#define E_EDGES 800000
#define NT 16                 // nodes per tile (one wave per tile)
#define NTILES (N_NODES / NT) // 6250
#define OFF_MU 6400000L
#define OFF_LV 8000000L

typedef __attribute__((ext_vector_type(8))) short short8;
typedef __attribute__((ext_vector_type(4))) float f32x4;
typedef __attribute__((ext_vector_type(4))) float float4v;

// packed-weight fragment regions (units: shorts; each frag = 64 lanes * 8 = 512)
#define SW_AGG 0
#define SW_FUS 8192
#define SW_W1  24576
#define SW_W2  32768
#define SW_W3  36864
#define SW_W4  40960
#define SW_TOT 49152          // 96 KB of shorts

#define PW_OFF (1 << 20)      // packed weights live at ws + 1 MB

__global__ void build_row_start(const int* __restrict__ edge_dst,
                                int* __restrict__ row_start) {
    int e = blockIdx.x * blockDim.x + threadIdx.x;
    if (e >= E_EDGES) return;
    int d = edge_dst[e];
    int dprev = (e == 0) ? -1 : edge_dst[e - 1];
    for (int n = dprev + 1; n <= d; ++n) row_start[n] = e;
    if (e == E_EDGES - 1) {
        for (int n = d + 1; n <= N_NODES; ++n) row_start[n] = E_EDGES;
    }
}

__device__ __forceinline__ unsigned short f2bf(float f) {
    unsigned u = __float_as_uint(f);
    unsigned r = u + 0x7FFFu + ((u >> 16) & 1u);
    return (unsigned short)(r >> 16);
}
__device__ __forceinline__ float bf2f(unsigned short h) {
    return __uint_as_float(((unsigned)h) << 16);
}
__device__ __forceinline__ void split8(const float* v, short8& hi, short8& lo) {
    #pragma unroll
    for (int i = 0; i < 8; ++i) {
        unsigned short h = f2bf(v[i]);
        hi[i] = (short)h;
        lo[i] = (short)f2bf(v[i] - bf2f(h));
    }
}

// XOR-swizzled activation tile address (16 rows x 64 f32 per wave)
__device__ __forceinline__ int actaddr(int row, int col) {
    return row * 64 + ((((col >> 2)) ^ (row & 15)) << 2) + (col & 3);
}

// pack one weight matrix into hi/lo bf16 B-fragment layout (dst may be global)
__device__ void stage_w(const float* __restrict__ W, int Ksrc, int NC,
                        int NKT, int NJT_local, int jt_off, int NF_tot,
                        int rb, short* sw, int tid) {
    const int tot = NJT_local * NKT * 64;
    for (int s = tid; s < tot; s += 512) {
        int f = s >> 6, l = s & 63;
        int jtl = f / NKT, kt = f - jtl * NKT;
        int col = jtl * 16 + (l & 15);
        int k0 = kt * 32 + ((l >> 4) << 3);
        float v[8];
        #pragma unroll
        for (int i = 0; i < 8; ++i)
            v[i] = (k0 + i < Ksrc) ? W[(k0 + i) * NC + col] : 0.0f;
        short8 hi, lo; split8(v, hi, lo);
        int fg = (jt_off + jtl) * NKT + kt;
        *(short8*)&sw[rb + fg * 512 + l * 8] = hi;
        *(short8*)&sw[rb + (NF_tot + fg) * 512 + l * 8] = lo;
    }
}

__global__ __launch_bounds__(512) void pack_weights(
    const float* __restrict__ W_agg, const float* __restrict__ W_fus,
    const float* __restrict__ W1,  const float* __restrict__ W21,
    const float* __restrict__ W22, const float* __restrict__ W3,
    const float* __restrict__ W4, short* __restrict__ gw) {
    const int tid = threadIdx.x;
    switch (blockIdx.x) {
        case 0: stage_w(W_agg, 64, 64, 2, 4, 0,  8, SW_AGG, gw, tid); break;
        case 1: stage_w(W_fus, 128, 64, 4, 4, 0, 16, SW_FUS, gw, tid); break;
        case 2: stage_w(W1,   64, 64, 2, 4, 0,  8, SW_W1,  gw, tid); break;
        case 3: stage_w(W21,  64, 16, 2, 1, 0,  4, SW_W2,  gw, tid); break;
        case 4: stage_w(W22,  64, 16, 2, 1, 1,  4, SW_W2,  gw, tid); break;
        case 5: stage_w(W3,   16, 64, 1, 4, 0,  4, SW_W3,  gw, tid); break;
        case 6: stage_w(W4,   64, 64, 2, 4, 0,  8, SW_W4,  gw, tid); break;
    }
}

// build A-frags (kt=0,1) for rows base..base+15 of a row-major [*,64] matrix
__device__ __forceinline__ void frags_from_global(const float* __restrict__ rowmat,
                                                  long base, int lane,
                                                  short8* hi, short8* lo) {
    const int row = lane & 15, ko = (lane >> 4) * 8;
    const float* r = rowmat + (base + row) * 64;
    float v[8];
    *(float4v*)&v[0] = *(const float4v*)&r[ko];
    *(float4v*)&v[4] = *(const float4v*)&r[ko + 4];
    split8(v, hi[0], lo[0]);
    *(float4v*)&v[0] = *(const float4v*)&r[32 + ko];
    *(float4v*)&v[4] = *(const float4v*)&r[32 + ko + 4];
    split8(v, hi[1], lo[1]);
}

template<int NKT>
__device__ __forceinline__ void frags_from_act(const float* actw, int lane,
                                               short8* hi, short8* lo) {
    const int row = lane & 15, ko = (lane >> 4) * 8;
    #pragma unroll
    for (int kt = 0; kt < NKT; ++kt) {
        float v[8];
        *(float4v*)&v[0] = *(const float4v*)&actw[actaddr(row, kt * 32 + ko)];
        *(float4v*)&v[4] = *(const float4v*)&actw[actaddr(row, kt * 32 + ko + 4)];
        split8(v, hi[kt], lo[kt]);
    }
}

// B-frags stream from global (L2-resident packed weights)
template<int NJT, int NKT>
__device__ __forceinline__ void gemm_frag(const short8* ahi, const short8* alo,
                                          const short* __restrict__ sw, int rb,
                                          const float* bj, f32x4* c, int lane) {
    #pragma unroll
    for (int jt = 0; jt < NJT; ++jt) {
        f32x4 acc = { bj[jt], bj[jt], bj[jt], bj[jt] };
        #pragma unroll
        for (int kt = 0; kt < NKT; ++kt) {
            const short8 bhi = *(const short8*)&sw[rb + (jt * NKT + kt) * 512 + lane * 8];
            const short8 blo = *(const short8*)&sw[rb + (NJT * NKT + jt * NKT + kt) * 512 + lane * 8];
            acc = __builtin_amdgcn_mfma_f32_16x16x32_bf16(ahi[kt], bhi, acc, 0, 0, 0);
            acc = __builtin_amdgcn_mfma_f32_16x16x32_bf16(alo[kt], bhi, acc, 0, 0, 0);
            acc = __builtin_amdgcn_mfma_f32_16x16x32_bf16(ahi[kt], blo, acc, 0, 0, 0);
        }
        c[jt] = acc;
    }
}

__device__ __forceinline__ void write_act(float* actw, const f32x4* c, int lane) {
    const int g = lane >> 4, col0 = lane & 15;
    #pragma unroll
    for (int jt = 0; jt < 4; ++jt)
        #pragma unroll
        for (int r = 0; r < 4; ++r)
            actw[actaddr(g * 4 + r, jt * 16 + col0)] = fmaxf(c[jt][r], 0.0f);
}

// edge index for tile-local edge te from preloaded lane regs (<192) else direct
__device__ __forceinline__ int get_idx(int te, int iv0, int iv1, int iv2,
                                       const int* __restrict__ edge_src, int E0) {
    if (te < 192) {
        const int w = te >> 6, l = te & 63;
        const int v = (w == 0) ? iv0 : ((w == 1) ? iv1 : iv2);
        return __builtin_amdgcn_readlane(v, l);
    }
    return edge_src[E0 + te];
}

__global__ __launch_bounds__(256, 4) void vae_top(
    const float* __restrict__ x,
    const int* __restrict__ edge_src,
    const float* __restrict__ eps,
    const float* __restrict__ b_agg, const float* __restrict__ b_fus,
    const float* __restrict__ b1,  const float* __restrict__ b21,
    const float* __restrict__ b22, const float* __restrict__ b3,
    const float* __restrict__ b4,
    const short* __restrict__ gw,
    const int* __restrict__ row_start,
    float* __restrict__ out)
{
    __shared__ __align__(16) float s_act[4 * 1024];   // 4 KB per wave, 16 KB total

    const int tid  = threadIdx.x;
    const int lane = tid & 63;
    const int wid  = tid >> 6;
    const int t    = blockIdx.x * 4 + wid;            // one tile per wave
    if (t >= NTILES) return;

    float* actw = s_act + wid * 1024;
    const int cj = lane & 15, g = lane >> 4;
    const int base = t * NT;

    // ---- per-lane bias registers ----
    float bja[4], bjf[4], bj1[4], bj2[2], bj3[4], bj4[4];
    #pragma unroll
    for (int jt = 0; jt < 4; ++jt) {
        bja[jt] = b_agg[jt * 16 + cj];
        bjf[jt] = b_fus[jt * 16 + cj];
        bj1[jt] = b1[jt * 16 + cj];
        bj3[jt] = b3[jt * 16 + cj];
        bj4[jt] = b4[jt * 16 + cj];
    }
    bj2[0] = b21[cj];
    bj2[1] = b22[cj];

    // ---- fused gather: segment mean into act tile (8-deep MLP) ----
    {
        int idx17 = base + (lane < 17 ? lane : 16);
        int rsv = row_start[idx17];
        const int E0 = __builtin_amdgcn_readlane(rsv, 0);

        int p0 = E0 + lane;       p0 = p0 < E_EDGES - 1 ? p0 : E_EDGES - 1;
        int p1 = E0 + 64 + lane;  p1 = p1 < E_EDGES - 1 ? p1 : E_EDGES - 1;
        int p2 = E0 + 128 + lane; p2 = p2 < E_EDGES - 1 ? p2 : E_EDGES - 1;
        const int iv0 = edge_src[p0];
        const int iv1 = edge_src[p1];
        const int iv2 = edge_src[p2];

        for (int n = 0; n < NT; ++n) {
            const int e0 = __builtin_amdgcn_readlane(rsv, n);
            const int e1 = __builtin_amdgcn_readlane(rsv, n + 1);
            float s0=0.f,s1=0.f,s2=0.f,s3=0.f,s4=0.f,s5=0.f,s6=0.f,s7=0.f;
            if (e1 > e0) {
                int e = e0;
                for (; e + 8 <= e1; e += 8) {
                    const int te = e - E0;
                    const int i0 = get_idx(te + 0, iv0, iv1, iv2, edge_src, E0);
                    const int i1 = get_idx(te + 1, iv0, iv1, iv2, edge_src, E0);
                    const int i2 = get_idx(te + 2, iv0, iv1, iv2, edge_src, E0);
                    const int i3 = get_idx(te + 3, iv0, iv1, iv2, edge_src, E0);
                    const int i4 = get_idx(te + 4, iv0, iv1, iv2, edge_src, E0);
                    const int i5 = get_idx(te + 5, iv0, iv1, iv2, edge_src, E0);
                    const int i6 = get_idx(te + 6, iv0, iv1, iv2, edge_src, E0);
                    const int i7 = get_idx(te + 7, iv0, iv1, iv2, edge_src, E0);
                    s0 += x[(long)i0 * 64 + lane];
                    s1 += x[(long)i1 * 64 + lane];
                    s2 += x[(long)i2 * 64 + lane];
                    s3 += x[(long)i3 * 64 + lane];
                    s4 += x[(long)i4 * 64 + lane];
                    s5 += x[(long)i5 * 64 + lane];
                    s6 += x[(long)i6 * 64 + lane];
                    s7 += x[(long)i7 * 64 + lane];
                }
                if (e < e1) {
                    #pragma unroll
                    for (int i = 0; i < 7; ++i) {
                        int ec = e + i;
                        const bool live = ec < e1;
                        ec = live ? ec : e0;
                        const int ix = get_idx(ec - E0, iv0, iv1, iv2, edge_src, E0);
                        float v = x[(long)ix * 64 + lane];
                        v = live ? v : 0.0f;
                        switch (i & 7) {
                            case 0: s0 += v; break; case 1: s1 += v; break;
                            case 2: s2 += v; break; case 3: s3 += v; break;
                            case 4: s4 += v; break; case 5: s5 += v; break;
                            case 6: s6 += v; break;
                        }
                    }
                }
            }
            const float sum = ((s0 + s1) + (s2 + s3)) + ((s4 + s5) + (s6 + s7));
            actw[actaddr(n, lane)] = sum / fmaxf((float)(e1 - e0), 1.0f);
        }
    }

    short8 ahi[4], alo[4];
    f32x4 c4[4];

    // ---- ne = relu(avg @ W_agg + b_agg) ----
    frags_from_act<2>(actw, lane, ahi, alo);
    gemm_frag<4, 2>(ahi, alo, gw, SW_AGG, bja, c4, lane);
    write_act(actw, c4, lane);                 // ne

    // ---- xf = relu([x, ne] @ W_fus + b_fus) ----
    frags_from_global(x, base, lane, ahi, alo);        // x part (kt 0,1)
    frags_from_act<2>(actw, lane, ahi + 2, alo + 2);   // ne part (kt 2,3)
    gemm_frag<4, 4>(ahi, alo, gw, SW_FUS, bjf, c4, lane);
    write_act(actw, c4, lane);                 // xf

    // ---- h1 = relu(xf @ W1 + b1) ----
    frags_from_act<2>(actw, lane, ahi, alo);
    gemm_frag<4, 2>(ahi, alo, gw, SW_W1, bj1, c4, lane);
    write_act(actw, c4, lane);                 // h1

    // ---- mu / logvar (combined 64x32 GEMM: jt0=mu, jt1=lv) ----
    frags_from_act<2>(actw, lane, ahi, alo);
    f32x4 c2[2];
    gemm_frag<2, 2>(ahi, alo, gw, SW_W2, bj2, c2, lane);

    // ---- store mu/lv; z = mu + eps*exp(0.5*lv) ----
    float z4[4];
    #pragma unroll
    for (int r = 0; r < 4; ++r) {
        const long node = base + g * 4 + r;
        out[OFF_MU + node * 16 + cj] = c2[0][r];
        out[OFF_LV + node * 16 + cj] = c2[1][r];
        z4[r] = c2[0][r] + eps[node * 16 + cj] * __expf(0.5f * c2[1][r]);
    }

    // ---- h3 = relu(z @ W3 + b3), K padded to 32 ----
    #pragma unroll
    for (int r = 0; r < 4; ++r)
        actw[actaddr(g * 4 + r, cj)] = z4[r];
    {
        short8 zh = {0,0,0,0,0,0,0,0}, zl = {0,0,0,0,0,0,0,0};
        if (lane < 32) {
            float v[8];
            const int row = lane & 15, ko = (lane >> 4) * 8;  // 0 or 8
            *(float4v*)&v[0] = *(const float4v*)&actw[actaddr(row, ko)];
            *(float4v*)&v[4] = *(const float4v*)&actw[actaddr(row, ko + 4)];
            split8(v, zh, zl);
        }
        gemm_frag<4, 1>(&zh, &zl, gw, SW_W3, bj3, c4, lane);
    }
    write_act(actw, c4, lane);                 // h3

    // ---- recon = sigmoid(h3 @ W4 + b4) ----
    frags_from_act<2>(actw, lane, ahi, alo);
    gemm_frag<4, 2>(ahi, alo, gw, SW_W4, bj4, c4, lane);
    #pragma unroll
    for (int jt = 0; jt < 4; ++jt)
        #pragma unroll
        for (int r = 0; r < 4; ++r) {
            const float s = 1.0f / (1.0f + __expf(-c4[jt][r]));
            out[(long)(base + g * 4 + r) * 64 + jt * 16 + cj] = s;
        }
}

extern "C" void kernel_launch(void* const* d_in, const int* in_sizes, int n_in,
                              void* d_out, int out_size, void* d_ws, size_t ws_size,
                              hipStream_t stream) {
    const float* x        = (const float*)d_in[0];
    const int*   edge_src = (const int*)  d_in[1];
    const int*   edge_dst = (const int*)  d_in[2];
    const float* eps      = (const float*)d_in[3];
    const float* W_agg    = (const float*)d_in[4];
    const float* b_agg    = (const float*)d_in[5];
    const float* W_fus    = (const float*)d_in[6];
    const float* b_fus    = (const float*)d_in[7];
    const float* W1       = (const float*)d_in[8];
    const float* b1       = (const float*)d_in[9];
    const float* W21      = (const float*)d_in[10];
    const float* b21      = (const float*)d_in[11];
    const float* W22      = (const float*)d_in[12];
    const float* b22      = (const float*)d_in[13];
    const float* W3       = (const float*)d_in[14];
    const float* b3       = (const float*)d_in[15];
    const float* W4       = (const float*)d_in[16];
    const float* b4       = (const float*)d_in[17];
    float* out = (float*)d_out;

    // ws layout: row_start [0, 400004B) ; packed weights at +1MB (96 KB).
    // ws_size proven >= 27 MB by rounds 5/6 (split path executed).
    int*   row_start = (int*)d_ws;
    short* gw        = (short*)((char*)d_ws + PW_OFF);

    build_row_start<<<(E_EDGES + 255) / 256, 256, 0, stream>>>(edge_dst, row_start);
    pack_weights<<<7, 512, 0, stream>>>(W_agg, W_fus, W1, W21, W22, W3, W4, gw);
    vae_top<<<(NTILES + 3) / 4, 256, 0, stream>>>(x, edge_src, eps,
                                                  b_agg, b_fus, b1, b21, b22, b3, b4,
                                                  gw, row_start, out);
}